// Round 2
// baseline (1118.775 us; speedup 1.0000x reference)
//
#include <hip/hip_runtime.h>
#include <hip/hip_bf16.h>
#include <stdint.h>

#define NN 10000
#define EE 50000
#define MP 50048   // EE padded to multiple of 128

typedef __hip_bfloat16 bf16_t;
typedef __attribute__((ext_vector_type(8))) short bf16x8;
typedef __attribute__((ext_vector_type(4))) float f32x4;

__device__ __forceinline__ float bf2f(unsigned short u) {
  union { unsigned int i; float f; } v; v.i = ((unsigned int)u) << 16; return v.f;
}

__device__ __forceinline__ void async_load16(const void* g, void* lds) {
  __builtin_amdgcn_global_load_lds((const __attribute__((address_space(1))) uint32_t*)g,
                                   (__attribute__((address_space(3))) uint32_t*)lds,
                                   16, 0, 0);
}

// C[M][N] = act(A[M][K] @ Bt[N][K]^T + bias[N]); A,Bt,C bf16 row-major, M,N mult of 128, K mult of 64.
// 128x128 tile, BK=64, 256 threads = 4 waves (2x2), each wave 64x64 (4x4 fragments of 16x16x32).
template <bool RELU>
__global__ __launch_bounds__(256, 2)
void gemm_bt(const bf16_t* __restrict__ A, const bf16_t* __restrict__ Bt,
             const float* __restrict__ bias, bf16_t* __restrict__ C,
             int N, int K) {
  __shared__ __align__(16) bf16_t As[128 * 64];
  __shared__ __align__(16) bf16_t Bs[128 * 64];

  const int t = threadIdx.x;
  const int lane = t & 63;
  const int wave = t >> 6;
  const int nt = N >> 7;
  const int bm = blockIdx.x / nt;
  const int bn = blockIdx.x % nt;
  const size_t aRowBase = (size_t)bm << 7;
  const size_t bRowBase = (size_t)bn << 7;

  const int wrBase = (wave >> 1) << 6;
  const int wcBase = (wave & 1) << 6;
  const int lo = lane & 15;
  const int hi = lane >> 4;

  f32x4 acc[4][4] = {};

  const int stg_r = t >> 3;   // row within 32-row issue chunk
  const int stg_s = t & 7;    // 16B slot within 128B row
  char* AsB = (char*)As;
  char* BsB = (char*)Bs;

  const int nkt = K >> 6;
  for (int kt = 0; kt < nkt; ++kt) {
    __syncthreads();
    #pragma unroll
    for (int it = 0; it < 4; ++it) {
      const int r = (it << 5) + stg_r;
      const int ls = (stg_s ^ (r & 7)) << 3;  // inverse-swizzled source element offset
      async_load16(A + (aRowBase + r) * K + (kt << 6) + ls,
                   AsB + (it << 12) + (wave << 10));
      async_load16(Bt + (bRowBase + r) * K + (kt << 6) + ls,
                   BsB + (it << 12) + (wave << 10));
    }
    __syncthreads();
    #pragma unroll
    for (int ks = 0; ks < 2; ++ks) {
      bf16x8 af[4], bfr[4];
      #pragma unroll
      for (int m = 0; m < 4; ++m) {
        const int row = wrBase + (m << 4) + lo;
        const int ps = ((ks << 2) + hi) ^ (row & 7);  // swizzled read slot
        af[m] = *(const bf16x8*)(AsB + (row << 7) + (ps << 4));
      }
      #pragma unroll
      for (int n = 0; n < 4; ++n) {
        const int row = wcBase + (n << 4) + lo;
        const int ps = ((ks << 2) + hi) ^ (row & 7);
        bfr[n] = *(const bf16x8*)(BsB + (row << 7) + (ps << 4));
      }
      #pragma unroll
      for (int m = 0; m < 4; ++m)
        #pragma unroll
        for (int n = 0; n < 4; ++n)
          acc[m][n] = __builtin_amdgcn_mfma_f32_16x16x32_bf16(af[m], bfr[n], acc[m][n], 0, 0, 0);
    }
  }

  // epilogue: C/D layout col=lane&15, row=(lane>>4)*4+j (m89-verified)
  #pragma unroll
  for (int m = 0; m < 4; ++m) {
    #pragma unroll
    for (int n = 0; n < 4; ++n) {
      const int col = (bn << 7) + wcBase + (n << 4) + lo;
      const float bv = bias[col];
      #pragma unroll
      for (int j = 0; j < 4; ++j) {
        const int row = (bm << 7) + wrBase + (m << 4) + (hi << 2) + j;
        float v = acc[m][n][j] + bv;
        if (RELU) v = fmaxf(v, 0.0f);
        C[(size_t)row * N + col] = __float2bfloat16(v);
      }
    }
  }
}

// wt[n*K + k] = bf16(w[k*N + n])  (transpose + cast)
__global__ void convert_t(const float* __restrict__ w, bf16_t* __restrict__ wt,
                          int K, int N) {
  int idx = blockIdx.x * 256 + threadIdx.x;
  if (idx >= K * N) return;
  int n = idx / K, k = idx - n * K;
  wt[idx] = __float2bfloat16(w[(size_t)k * N + n]);
}

__global__ void fc1_kernel(const float* __restrict__ x, const float* __restrict__ w,
                           const float* __restrict__ b, float* __restrict__ h) {
  int idx = blockIdx.x * 256 + threadIdx.x;
  if (idx >= NN * 64) return;
  int n = idx >> 6, j = idx & 63;
  h[idx] = fmaf(x[n], w[j], b[j]);
}

__global__ void deg_kernel(const int* __restrict__ ei, float* __restrict__ deg) {
  int e = blockIdx.x * 256 + threadIdx.x;
  if (e < EE) {
    unsigned d = (unsigned)ei[EE + e];
    if (d < NN) atomicAdd(&deg[d], 1.0f);
  }
}

// e1[el][0:256] = relu(attr[e0+el] @ k1_w + k1_b), zeros for rows >= ne
__global__ void k1_kernel(const float* __restrict__ attr, const float* __restrict__ w,
                          const float* __restrict__ b, bf16_t* __restrict__ e1,
                          int e0, int ne) {
  const int el = blockIdx.x;
  const int j = threadIdx.x;
  __shared__ float a[6];
  if (el < ne && j < 6) a[j] = attr[(size_t)(e0 + el) * 6 + j];
  __syncthreads();
  float v = 0.0f;
  if (el < ne) {
    v = b[j];
    #pragma unroll
    for (int i = 0; i < 6; ++i) v = fmaf(a[i], w[i * 256 + j], v);
    v = fmaxf(v, 0.0f);
  }
  e1[(size_t)el * 256 + j] = __float2bfloat16(v);
}

// per-edge matvec msg[o] = sum_i h[src][i] * W[el][i*64+o], atomic scatter to agg[dst]
__global__ __launch_bounds__(256)
void msg_kernel(const float* __restrict__ h, const bf16_t* __restrict__ W,
                const int* __restrict__ ei, float* __restrict__ agg,
                int e0, int ne) {
  const int el = blockIdx.x * 4 + (threadIdx.x >> 6);
  if (el >= ne) return;
  const int e = e0 + el;
  const int lane = threadIdx.x & 63;
  const int g = lane >> 4, c = lane & 15;
  const unsigned src = (unsigned)ei[e], dst = (unsigned)ei[EE + e];
  if (src >= NN || dst >= NN) return;  // hardening: degrade, don't fault
  const float hv = h[src * 64 + lane];
  const unsigned short* We = (const unsigned short*)(W + (size_t)el * 4096);
  float a0 = 0, a1 = 0, a2 = 0, a3 = 0;
  #pragma unroll
  for (int i0 = 0; i0 < 64; i0 += 4) {
    const int i = i0 + g;
    const float hs = __shfl(hv, i);
    ushort4 wv = *(const ushort4*)(We + i * 64 + c * 4);
    a0 = fmaf(hs, bf2f(wv.x), a0);
    a1 = fmaf(hs, bf2f(wv.y), a1);
    a2 = fmaf(hs, bf2f(wv.z), a2);
    a3 = fmaf(hs, bf2f(wv.w), a3);
  }
  a0 += __shfl_xor(a0, 16); a0 += __shfl_xor(a0, 32);
  a1 += __shfl_xor(a1, 16); a1 += __shfl_xor(a1, 32);
  a2 += __shfl_xor(a2, 16); a2 += __shfl_xor(a2, 32);
  a3 += __shfl_xor(a3, 16); a3 += __shfl_xor(a3, 32);
  if (g == 0) {
    float* ag = agg + (size_t)dst * 64 + c * 4;
    atomicAdd(ag + 0, a0);
    atomicAdd(ag + 1, a1);
    atomicAdd(ag + 2, a2);
    atomicAdd(ag + 3, a3);
  }
}

// h_new = relu(agg/deg + h @ root + gcn_b)
__global__ __launch_bounds__(256)
void update_kernel(const float* __restrict__ h, const float* __restrict__ agg,
                   const float* __restrict__ deg, const float* __restrict__ root,
                   const float* __restrict__ gb, float* __restrict__ hn) {
  const int n = blockIdx.x * 4 + (threadIdx.x >> 6);
  if (n >= NN) return;
  const int lane = threadIdx.x & 63;
  const float hv = h[n * 64 + lane];
  float acc = 0.0f;
  #pragma unroll
  for (int i = 0; i < 64; ++i)
    acc = fmaf(__shfl(hv, i), root[i * 64 + lane], acc);
  const float d = fmaxf(deg[n], 1.0f);
  const float v = agg[n * 64 + lane] / d + acc + gb[lane];
  hn[n * 64 + lane] = fmaxf(v, 0.0f);
}

__global__ __launch_bounds__(256)
void fc2_kernel(const float* __restrict__ h, const float* __restrict__ w,
                const float* __restrict__ b, float* __restrict__ out) {
  const int n = blockIdx.x * 4 + (threadIdx.x >> 6);
  if (n >= NN) return;
  const int lane = threadIdx.x & 63;
  float v = h[n * 64 + lane] * w[lane];
  #pragma unroll
  for (int off = 32; off > 0; off >>= 1) v += __shfl_xor(v, off);
  if (lane == 0) out[n] = v + b[0];
}

extern "C" void kernel_launch(void* const* d_in, const int* in_sizes, int n_in,
                              void* d_out, int out_size, void* d_ws, size_t ws_size,
                              hipStream_t stream) {
  const float* x     = (const float*)d_in[0];
  const int*   ei    = (const int*)d_in[1];
  const float* attr  = (const float*)d_in[2];
  const float* fc1_w = (const float*)d_in[3];
  const float* fc1_b = (const float*)d_in[4];
  const float* k1_w  = (const float*)d_in[5];
  const float* k1_b  = (const float*)d_in[6];
  const float* k2_w  = (const float*)d_in[7];
  const float* k2_b  = (const float*)d_in[8];
  const float* k3_w  = (const float*)d_in[9];
  const float* k3_b  = (const float*)d_in[10];
  const float* root  = (const float*)d_in[11];
  const float* gcn_b = (const float*)d_in[12];
  const float* fc2_w = (const float*)d_in[13];
  const float* fc2_b = (const float*)d_in[14];
  float* out = (float*)d_out;
  (void)in_sizes; (void)n_in; (void)out_size;

  char* ws = (char*)d_ws;
  size_t off = 0;
  auto take = [&](size_t bytes) -> char* {
    char* p = ws + off;
    off += (bytes + 255) & ~(size_t)255;
    return p;
  };
  // fixed small buffers first (~12.3 MB)
  bf16_t* k2wt = (bf16_t*)take((size_t)512 * 256 * 2);
  bf16_t* k3wt = (bf16_t*)take((size_t)4096 * 512 * 2);
  float*  hA   = (float*)take((size_t)NN * 64 * 4);
  float*  hB   = (float*)take((size_t)NN * 64 * 4);
  float*  agg  = (float*)take((size_t)NN * 64 * 4);
  float*  deg  = (float*)take((size_t)NN * 4);

  // adaptive edge-chunk capacity: e1(512B) + e2(1KB) + W(8KB) per edge = 9728 B
  const size_t per_edge = (256 + 512 + 4096) * 2;
  size_t avail = (ws_size > off + 4096) ? (ws_size - off - 4096) : 0;
  long cap = (long)(avail / per_edge);
  int Ec = (int)(cap / 128) * 128;
  if (Ec > MP) Ec = MP;
  if (Ec < 128) Ec = 128;  // below this nothing works; fail loudly via OOB-free minimal run
  bf16_t* e1 = (bf16_t*)take((size_t)Ec * 256 * 2);
  bf16_t* e2 = (bf16_t*)take((size_t)Ec * 512 * 2);
  bf16_t* Wc = (bf16_t*)take((size_t)Ec * 4096 * 2);

  // weight transposes + casts
  convert_t<<<(512 * 256 + 255) / 256, 256, 0, stream>>>(k2_w, k2wt, 256, 512);
  convert_t<<<(4096 * 512 + 255) / 256, 256, 0, stream>>>(k3_w, k3wt, 512, 4096);

  // h0 = x @ fc1_w + fc1_b
  fc1_kernel<<<(NN * 64 + 255) / 256, 256, 0, stream>>>(x, fc1_w, fc1_b, hA);

  // in-degree
  hipMemsetAsync(deg, 0, NN * 4, stream);
  deg_kernel<<<(EE + 255) / 256, 256, 0, stream>>>(ei, deg);

  const bool fullW = (Ec >= MP);
  if (fullW) {
    // edge MLP once, W reused across layers
    k1_kernel<<<MP, 256, 0, stream>>>(attr, k1_w, k1_b, e1, 0, EE);
    gemm_bt<true><<<(MP >> 7) * 4, 256, 0, stream>>>(e1, k2wt, k2_b, e2, 512, 256);
    gemm_bt<false><<<(MP >> 7) * 32, 256, 0, stream>>>(e2, k3wt, k3_b, Wc, 4096, 512);
  }

  float* hc = hA;
  float* hn = hB;
  for (int l = 0; l < 3; ++l) {
    hipMemsetAsync(agg, 0, (size_t)NN * 64 * 4, stream);
    if (fullW) {
      msg_kernel<<<(EE + 3) / 4, 256, 0, stream>>>(hc, Wc, ei, agg, 0, EE);
    } else {
      for (int e0 = 0; e0 < EE; e0 += Ec) {
        int ne = EE - e0; if (ne > Ec) ne = Ec;
        int nep = (ne + 127) & ~127;
        k1_kernel<<<nep, 256, 0, stream>>>(attr, k1_w, k1_b, e1, e0, ne);
        gemm_bt<true><<<(nep >> 7) * 4, 256, 0, stream>>>(e1, k2wt, k2_b, e2, 512, 256);
        gemm_bt<false><<<(nep >> 7) * 32, 256, 0, stream>>>(e2, k3wt, k3_b, Wc, 4096, 512);
        msg_kernel<<<(ne + 3) / 4, 256, 0, stream>>>(hc, Wc, ei, agg, e0, ne);
      }
    }
    update_kernel<<<(NN + 3) / 4, 256, 0, stream>>>(hc, agg, deg, root, gcn_b, hn);
    float* tmp = hc; hc = hn; hn = tmp;
  }

  fc2_kernel<<<(NN + 3) / 4, 256, 0, stream>>>(hc, fc2_w, fc2_b, out);
}